// Round 3
// baseline (326.908 us; speedup 1.0000x reference)
//
#include <hip/hip_runtime.h>

#define HIDDEN   128
#define TPB      1024
#define PPT      12              // paths/thread: 36 ids + 12 acc + temps, VGPR<=64
#define CN       38400           // nodes per plane-chunk (single l) staged in LDS
#define CN2      76800           // bytes per full plane-chunk (CN * 2) = 75 KiB
#define DUMMY2   76800           // byte offset of the zeroed dummy slot
#define UNITS    (CN2 / 1024)    // 75 x 1KB wave-units per full chunk

typedef unsigned short u16;
typedef unsigned int   u32;

static __device__ __forceinline__ u16 f32_to_f16_bits(float x) {
    union { _Float16 h; u16 u; } cv;
    cv.h = (_Float16)x;
    return cv.u;
}

// Async global->LDS DMA, 16 B per lane: lane i's 16 B from its own global
// address land at (wave-uniform lds base) + i*16.
static __device__ __forceinline__ void gload_lds16(const void* gp, void* lp) {
    __builtin_amdgcn_global_load_lds(
        (const __attribute__((address_space(1))) unsigned int*)gp,
        (__attribute__((address_space(3))) unsigned int*)lp,
        16, 0, 0);
}

// Kernel 1: f16 projection table in PLANE-MAJOR layout:
//   proj_h[l * n_nodes + node]  (3 planes of n_nodes f16 each, 600000 B total).
// One wave per node. Fill overread (last chunk rounds to 1 KB units) stays
// under the 614400 B workspace budget: max read end = 2*200000+153600+47104
// = 600704 B.
__global__ __launch_bounds__(256) void proj_kernel(
    const float* __restrict__ feat,   // (n_nodes, 128)
    const float* __restrict__ W,      // (3, 1, 128)
    u16* __restrict__ proj_h,         // 3 * n_nodes f16, plane-major
    int n_nodes)
{
    int gtid = blockIdx.x * blockDim.x + threadIdx.x;
    int node = gtid >> 6;
    int lane = threadIdx.x & 63;
    if (node >= n_nodes) return;

    const float2* f2 = (const float2*)(feat + (size_t)node * HIDDEN);
    const float2* w2 = (const float2*)W;

    float2 f   = f2[lane];
    float2 w0  = w2[lane];           // W[0]
    float2 w1  = w2[64 + lane];      // W[1]
    float2 wv2 = w2[128 + lane];     // W[2]

    float s0 = f.x * w0.x  + f.y * w0.y;
    float s1 = f.x * w1.x  + f.y * w1.y;
    float s2 = f.x * wv2.x + f.y * wv2.y;

    #pragma unroll
    for (int off = 32; off > 0; off >>= 1) {
        s0 += __shfl_xor(s0, off, 64);
        s1 += __shfl_xor(s1, off, 64);
        s2 += __shfl_xor(s2, off, 64);
    }

    if (lane == 0) {
        u16* base = proj_h + node;
        base[0]                   = f32_to_f16_bits(s0);
        base[n_nodes]             = f32_to_f16_bits(s1);
        base[2 * (size_t)n_nodes] = f32_to_f16_bits(s2);
    }
}

// Kernel 2: plane-split chunk passes, BLOCK-STRIDED path assignment,
// TWO BLOCKS PER CU. Round 2 showed the kernel is barrier-serialized:
// 102 KiB LDS forced 1 block/CU, so every __syncthreads (with its implicit
// vmcnt(0) drain of the fill DMA) stalled the whole CU (Occ 33%, VALU 23%,
// HBM 17% — nothing saturated). Chunk shrunk to 75 KiB so 2 blocks co-reside
// (2 x 76804 B LDS, 32 waves/CU, VGPR 56 <= 64 for 8 waves/SIMD): while one
// block drains a barrier the other keeps issuing. Cost: nh=3 -> 9 passes,
// 108 attempts/thread (VALU was only 23% busy — headroom).
__global__ __launch_bounds__(TPB, 8) void score_kernel(
    const int* __restrict__ paths,    // (n_paths, 3) int32
    const u16* __restrict__ proj_h,   // plane-major f16 table
    float* __restrict__ out,          // (n_paths,)
    int n_paths, int n_nodes, int nh)
{
    extern __shared__ u16 lds[];              // CN2 bytes + 4 (dummy)
    char* ldsb = (char*)lds;

    int base = blockIdx.x * (TPB * PPT) + threadIdx.x;
    int wid  = threadIdx.x >> 6;
    int lane = threadIdx.x & 63;

    // ids pre-doubled (byte offsets, sign preserved: -1 -> -2). Static indices.
    int id2[3 * PPT];
    #pragma unroll
    for (int k = 0; k < PPT; ++k) {
        int idx = base + k * TPB;
        int ii  = idx < n_paths ? idx : (n_paths - 1);   // clamp: uniform flow
        const int* pp = paths + (size_t)ii * 3;
        id2[3*k+0] = __builtin_nontemporal_load(pp + 0) << 1;
        id2[3*k+1] = __builtin_nontemporal_load(pp + 1) << 1;
        id2[3*k+2] = __builtin_nontemporal_load(pp + 2) << 1;
    }

    if (threadIdx.x == 0) lds[DUMMY2 / 2] = 0;   // visible after first barrier

    float acc[PPT];
    #pragma unroll
    for (int k = 0; k < PPT; ++k) acc[k] = 0.0f;

    const unsigned char* tab = (const unsigned char*)proj_h;
    int plane_b = 2 * n_nodes;                   // bytes per plane (200000)

    for (int h = 0; h < nh; ++h) {
        int cb2   = h * CN2;
        int rem_b = plane_b - cb2;               // bytes left in a plane
        int units = rem_b >= CN2 ? UNITS : ((rem_b + 1023) >> 10);

        #pragma unroll
        for (int l = 0; l < 3; ++l) {
            // Async fill: stage plane l, nodes [h*CN, h*CN+CN) — zero waits.
            const unsigned char* src = tab + (size_t)l * plane_b + cb2;
            for (int j = wid; j < units; j += TPB / 64)
                gload_lds16(src + (size_t)j * 1024 + lane * 16,
                            ldsb + j * 1024);
            __syncthreads();                     // drains vmcnt: fill complete

            // One attempt per path: sub, cmp, cndmask, ds_read_u16, cvt, add.
            #pragma unroll
            for (int k = 0; k < PPT; ++k) {
                u32 loc2 = (u32)(id2[3*k + l] - cb2);  // miss/-1 => huge => dummy
                int off  = loc2 < (u32)CN2 ? (int)loc2 : DUMMY2;
                union { u16 u; _Float16 hh; } cv;
                cv.u = *(const u16*)(ldsb + off);
                acc[k] += (float)cv.hh;
            }
            if (h + 1 < nh || l < 2) __syncthreads();  // reads done before next fill
        }
    }

    #pragma unroll
    for (int k = 0; k < PPT; ++k) {
        int idx = base + k * TPB;
        if (idx < n_paths) {
            int cnt = (int)(id2[3*k] >= 0) + (int)(id2[3*k+1] >= 0)
                    + (int)(id2[3*k+2] >= 0);
            float inv = (cnt == 3) ? (1.0f/3.0f) : (cnt == 2 ? 0.5f : 1.0f);
            __builtin_nontemporal_store(acc[k] * inv, out + idx);
        }
    }
}

extern "C" void kernel_launch(void* const* d_in, const int* in_sizes, int n_in,
                              void* d_out, int out_size, void* d_ws, size_t ws_size,
                              hipStream_t stream) {
    const int*   paths = (const int*)d_in[0];     // (N_PATHS, 3) int32
    const float* feat  = (const float*)d_in[1];   // (N_NODES, 128) f32
    const float* W     = (const float*)d_in[2];   // (3, 1, 128) f32
    float*       out   = (float*)d_out;           // (N_PATHS,) f32

    int n_nodes = in_sizes[1] / HIDDEN;           // 100000
    int n_paths = in_sizes[0] / 3;                // 10000000
    u16* proj_h = (u16*)d_ws;                     // 3 planes * n_nodes f16

    int nh = (n_nodes + CN - 1) / CN;             // 3 plane-chunks per plane
    size_t lds_bytes = (size_t)CN2 + 4;           // 76804 -> 2 blocks/CU

    (void)hipFuncSetAttribute((const void*)score_kernel,
            hipFuncAttributeMaxDynamicSharedMemorySize, (int)lds_bytes);
    (void)hipGetLastError();   // clear any sticky error pre-capture

    // Kernel 1: 1 wave per node, 4 waves per 256-thread block.
    {
        int blocks = (n_nodes + 3) / 4;
        proj_kernel<<<blocks, 256, 0, stream>>>(feat, W, proj_h, n_nodes);
    }

    // Kernel 2: 814 blocks at 2/CU — cross-block overlap hides barrier drains.
    {
        int blocks = (n_paths + TPB * PPT - 1) / (TPB * PPT);  // 814
        score_kernel<<<blocks, TPB, lds_bytes, stream>>>(paths, proj_h, out,
                                                         n_paths, n_nodes, nh);
    }
}

// Round 4
// 261.426 us; speedup vs baseline: 1.2505x; 1.2505x over previous
//
#include <hip/hip_runtime.h>

#define HIDDEN   128
#define TPB      1024
#define PPT      12              // paths/thread: 36 ids + 12 acc + temps, VGPR~56
#define CN       38400           // nodes per plane-chunk (single l) staged in LDS
#define CN2      76800           // bytes per full plane-chunk (CN * 2) = 75 KiB
#define DUMMY2   76800           // byte offset of the zeroed dummy slot
#define UNITS    (CN2 / 1024)    // 75 x 1KB wave-units per full chunk

typedef unsigned short u16;
typedef unsigned int   u32;

static __device__ __forceinline__ u16 f32_to_f16_bits(float x) {
    union { _Float16 h; u16 u; } cv;
    cv.h = (_Float16)x;
    return cv.u;
}

// Async global->LDS DMA, 16 B per lane: lane i's 16 B from its own global
// address land at (wave-uniform lds base) + i*16.
static __device__ __forceinline__ void gload_lds16(const void* gp, void* lp) {
    __builtin_amdgcn_global_load_lds(
        (const __attribute__((address_space(1))) unsigned int*)gp,
        (__attribute__((address_space(3))) unsigned int*)lp,
        16, 0, 0);
}

// Kernel 1: f16 projection table in PLANE-MAJOR layout:
//   proj_h[l * n_nodes + node]  (3 planes of n_nodes f16 each, 600000 B total).
// One wave per node. Fill overread (last chunk rounds to 1 KB units) stays
// under the 614400 B workspace budget: max read end = 2*200000+200704
// = 600704 B.
__global__ __launch_bounds__(256) void proj_kernel(
    const float* __restrict__ feat,   // (n_nodes, 128)
    const float* __restrict__ W,      // (3, 1, 128)
    u16* __restrict__ proj_h,         // 3 * n_nodes f16, plane-major
    int n_nodes)
{
    int gtid = blockIdx.x * blockDim.x + threadIdx.x;
    int node = gtid >> 6;
    int lane = threadIdx.x & 63;
    if (node >= n_nodes) return;

    const float2* f2 = (const float2*)(feat + (size_t)node * HIDDEN);
    const float2* w2 = (const float2*)W;

    float2 f   = f2[lane];
    float2 w0  = w2[lane];           // W[0]
    float2 w1  = w2[64 + lane];      // W[1]
    float2 wv2 = w2[128 + lane];     // W[2]

    float s0 = f.x * w0.x  + f.y * w0.y;
    float s1 = f.x * w1.x  + f.y * w1.y;
    float s2 = f.x * wv2.x + f.y * wv2.y;

    #pragma unroll
    for (int off = 32; off > 0; off >>= 1) {
        s0 += __shfl_xor(s0, off, 64);
        s1 += __shfl_xor(s1, off, 64);
        s2 += __shfl_xor(s2, off, 64);
    }

    if (lane == 0) {
        u16* base = proj_h + node;
        base[0]                   = f32_to_f16_bits(s0);
        base[n_nodes]             = f32_to_f16_bits(s1);
        base[2 * (size_t)n_nodes] = f32_to_f16_bits(s2);
    }
}

// Kernel 2: plane-split chunk passes, BLOCK-STRIDED path assignment,
// TWO BLOCKS PER CU via 75 KiB LDS chunks.
//
// History of this config (the two knobs are now isolated):
//  - R2: CN=51200 (1 blk/CU), bounds (TPB,4): VGPR=56, no spill, 72 us —
//        barrier-serialized (Occ 33%).
//  - R3: CN=38400 (2 blk/CU), bounds (TPB,8): Occ hit 73% BUT the reg cap
//        dropped VGPR to 32 -> id2[] spilled (WRITE 211 MB, FETCH 290 MB),
//        149 us. Occupancy goal proven, register cap poisoned it.
//  - Now: CN=38400 + bounds (TPB,4): VGPR~56 (<=64 still allows 8 waves/SIMD
//        = both resident blocks runnable), no spill + cross-block overlap.
__global__ __launch_bounds__(TPB, 4) void score_kernel(
    const int* __restrict__ paths,    // (n_paths, 3) int32
    const u16* __restrict__ proj_h,   // plane-major f16 table
    float* __restrict__ out,          // (n_paths,)
    int n_paths, int n_nodes, int nh)
{
    extern __shared__ u16 lds[];              // CN2 bytes + 4 (dummy)
    char* ldsb = (char*)lds;

    int base = blockIdx.x * (TPB * PPT) + threadIdx.x;
    int wid  = threadIdx.x >> 6;
    int lane = threadIdx.x & 63;

    // ids pre-doubled (byte offsets, sign preserved: -1 -> -2). Static indices.
    int id2[3 * PPT];
    #pragma unroll
    for (int k = 0; k < PPT; ++k) {
        int idx = base + k * TPB;
        int ii  = idx < n_paths ? idx : (n_paths - 1);   // clamp: uniform flow
        const int* pp = paths + (size_t)ii * 3;
        id2[3*k+0] = __builtin_nontemporal_load(pp + 0) << 1;
        id2[3*k+1] = __builtin_nontemporal_load(pp + 1) << 1;
        id2[3*k+2] = __builtin_nontemporal_load(pp + 2) << 1;
    }

    if (threadIdx.x == 0) lds[DUMMY2 / 2] = 0;   // visible after first barrier

    float acc[PPT];
    #pragma unroll
    for (int k = 0; k < PPT; ++k) acc[k] = 0.0f;

    const unsigned char* tab = (const unsigned char*)proj_h;
    int plane_b = 2 * n_nodes;                   // bytes per plane (200000)

    for (int h = 0; h < nh; ++h) {
        int cb2   = h * CN2;
        int rem_b = plane_b - cb2;               // bytes left in a plane
        int units = rem_b >= CN2 ? UNITS : ((rem_b + 1023) >> 10);

        #pragma unroll
        for (int l = 0; l < 3; ++l) {
            // Async fill: stage plane l, nodes [h*CN, h*CN+CN) — zero waits.
            const unsigned char* src = tab + (size_t)l * plane_b + cb2;
            for (int j = wid; j < units; j += TPB / 64)
                gload_lds16(src + (size_t)j * 1024 + lane * 16,
                            ldsb + j * 1024);
            __syncthreads();                     // drains vmcnt: fill complete

            // One attempt per path: sub, cmp, cndmask, ds_read_u16, cvt, add.
            #pragma unroll
            for (int k = 0; k < PPT; ++k) {
                u32 loc2 = (u32)(id2[3*k + l] - cb2);  // miss/-1 => huge => dummy
                int off  = loc2 < (u32)CN2 ? (int)loc2 : DUMMY2;
                union { u16 u; _Float16 hh; } cv;
                cv.u = *(const u16*)(ldsb + off);
                acc[k] += (float)cv.hh;
            }
            if (h + 1 < nh || l < 2) __syncthreads();  // reads done before next fill
        }
    }

    #pragma unroll
    for (int k = 0; k < PPT; ++k) {
        int idx = base + k * TPB;
        if (idx < n_paths) {
            int cnt = (int)(id2[3*k] >= 0) + (int)(id2[3*k+1] >= 0)
                    + (int)(id2[3*k+2] >= 0);
            float inv = (cnt == 3) ? (1.0f/3.0f) : (cnt == 2 ? 0.5f : 1.0f);
            __builtin_nontemporal_store(acc[k] * inv, out + idx);
        }
    }
}

extern "C" void kernel_launch(void* const* d_in, const int* in_sizes, int n_in,
                              void* d_out, int out_size, void* d_ws, size_t ws_size,
                              hipStream_t stream) {
    const int*   paths = (const int*)d_in[0];     // (N_PATHS, 3) int32
    const float* feat  = (const float*)d_in[1];   // (N_NODES, 128) f32
    const float* W     = (const float*)d_in[2];   // (3, 1, 128) f32
    float*       out   = (float*)d_out;           // (N_PATHS,) f32

    int n_nodes = in_sizes[1] / HIDDEN;           // 100000
    int n_paths = in_sizes[0] / 3;                // 10000000
    u16* proj_h = (u16*)d_ws;                     // 3 planes * n_nodes f16

    int nh = (n_nodes + CN - 1) / CN;             // 3 plane-chunks per plane
    size_t lds_bytes = (size_t)CN2 + 4;           // 76804 -> 2 blocks/CU

    (void)hipFuncSetAttribute((const void*)score_kernel,
            hipFuncAttributeMaxDynamicSharedMemorySize, (int)lds_bytes);
    (void)hipGetLastError();   // clear any sticky error pre-capture

    // Kernel 1: 1 wave per node, 4 waves per 256-thread block.
    {
        int blocks = (n_nodes + 3) / 4;
        proj_kernel<<<blocks, 256, 0, stream>>>(feat, W, proj_h, n_nodes);
    }

    // Kernel 2: 814 blocks at 2/CU — cross-block overlap hides barrier drains.
    {
        int blocks = (n_paths + TPB * PPT - 1) / (TPB * PPT);  // 814
        score_kernel<<<blocks, TPB, lds_bytes, stream>>>(paths, proj_h, out,
                                                         n_paths, n_nodes, nh);
    }
}

// Round 5
// 254.271 us; speedup vs baseline: 1.2857x; 1.0281x over previous
//
#include <hip/hip_runtime.h>

#define HIDDEN   128
#define TPB      1024
#define PPT      12              // paths/thread: 36 ids + 12 acc + temps, VGPR~56
#define CN       38400           // nodes per plane-chunk (single l) staged in LDS
#define CN2      76800           // bytes per full plane-chunk (CN * 2) = 75 KiB
#define DUMMY2   (2 * CN2)       // byte offset of zero slot (after both buffers)
#define UNITS    (CN2 / 1024)    // 75 x 1KB wave-units per full chunk

typedef unsigned short u16;
typedef unsigned int   u32;

static __device__ __forceinline__ u16 f32_to_f16_bits(float x) {
    union { _Float16 h; u16 u; } cv;
    cv.h = (_Float16)x;
    return cv.u;
}

// Async global->LDS DMA, 16 B per lane: lane i's 16 B from its own global
// address land at (wave-uniform lds base) + i*16.
static __device__ __forceinline__ void gload_lds16(const void* gp, void* lp) {
    __builtin_amdgcn_global_load_lds(
        (const __attribute__((address_space(1))) unsigned int*)gp,
        (__attribute__((address_space(3))) unsigned int*)lp,
        16, 0, 0);
}

// Kernel 1: f16 projection table in PLANE-MAJOR layout:
//   proj_h[l * n_nodes + node]  (3 planes of n_nodes f16 each, 600000 B total).
// One wave per node. Fill overread (last chunk rounds to 1 KB units) stays
// under the workspace budget: max read end = 2*200000 + 153600 + 47104
// = 600704 B.
__global__ __launch_bounds__(256) void proj_kernel(
    const float* __restrict__ feat,   // (n_nodes, 128)
    const float* __restrict__ W,      // (3, 1, 128)
    u16* __restrict__ proj_h,         // 3 * n_nodes f16, plane-major
    int n_nodes)
{
    int gtid = blockIdx.x * blockDim.x + threadIdx.x;
    int node = gtid >> 6;
    int lane = threadIdx.x & 63;
    if (node >= n_nodes) return;

    const float2* f2 = (const float2*)(feat + (size_t)node * HIDDEN);
    const float2* w2 = (const float2*)W;

    float2 f   = f2[lane];
    float2 w0  = w2[lane];           // W[0]
    float2 w1  = w2[64 + lane];      // W[1]
    float2 wv2 = w2[128 + lane];     // W[2]

    float s0 = f.x * w0.x  + f.y * w0.y;
    float s1 = f.x * w1.x  + f.y * w1.y;
    float s2 = f.x * wv2.x + f.y * wv2.y;

    #pragma unroll
    for (int off = 32; off > 0; off >>= 1) {
        s0 += __shfl_xor(s0, off, 64);
        s1 += __shfl_xor(s1, off, 64);
        s2 += __shfl_xor(s2, off, 64);
    }

    if (lane == 0) {
        u16* base = proj_h + node;
        base[0]                   = f32_to_f16_bits(s0);
        base[n_nodes]             = f32_to_f16_bits(s1);
        base[2 * (size_t)n_nodes] = f32_to_f16_bits(s2);
    }
}

// Kernel 2: plane-split chunk passes, DOUBLE-BUFFERED LDS.
//
// R4 post-mortem: 2 blocks/CU is unreachable (needs VGPR<=~48 for 8 waves/
// SIMD; 36 ids + 12 acc can't fit -> R3 spilled at the capped 32). So the
// per-pass serial chain  fill-issue -> DMA wait -> barrier -> gather  is
// instead pipelined WITHIN the single resident block: two 75 KiB buffers;
// pass c issues the async fill of chunk c+1 into buf[(c+1)&1], gathers
// chunk c from buf[c&1], then barriers — the vmcnt(0) drain at the barrier
// happens a full gather-phase after the DMA was issued, so it is nearly
// free. LDS = 2*76800 + 4 = 153604 B (1 block/CU, same as R4's occupancy).
// Plane loop stays compile-time-unrolled so id2[] indices remain static
// (runtime-indexed reg arrays spill to scratch).
__global__ __launch_bounds__(TPB, 4) void score_kernel(
    const int* __restrict__ paths,    // (n_paths, 3) int32
    const u16* __restrict__ proj_h,   // plane-major f16 table
    float* __restrict__ out,          // (n_paths,)
    int n_paths, int n_nodes, int nh)
{
    extern __shared__ u16 lds[];              // 2*CN2 bytes + 4 (dummy)
    char* ldsb = (char*)lds;

    int base = blockIdx.x * (TPB * PPT) + threadIdx.x;
    int wid  = threadIdx.x >> 6;
    int lane = threadIdx.x & 63;

    const unsigned char* tab = (const unsigned char*)proj_h;
    int plane_b = 2 * n_nodes;                   // bytes per plane (200000)
    int NC      = 3 * nh;                        // total chunks (9)

    // Prologue: start the DMA for chunk 0 (h=0, l=0) into buffer 0 FIRST,
    // so it overlaps the 36 path loads below.
    {
        int units0 = plane_b >= CN2 ? UNITS : ((plane_b + 1023) >> 10);
        for (int j = wid; j < units0; j += TPB / 64)
            gload_lds16(tab + (size_t)j * 1024 + lane * 16,
                        ldsb + j * 1024);
    }
    if (threadIdx.x == 0) lds[DUMMY2 / 2] = 0;   // visible after first barrier

    // ids pre-doubled (byte offsets, sign preserved: -1 -> -2). Static indices.
    int id2[3 * PPT];
    #pragma unroll
    for (int k = 0; k < PPT; ++k) {
        int idx = base + k * TPB;
        int ii  = idx < n_paths ? idx : (n_paths - 1);   // clamp: uniform flow
        const int* pp = paths + (size_t)ii * 3;
        id2[3*k+0] = __builtin_nontemporal_load(pp + 0) << 1;
        id2[3*k+1] = __builtin_nontemporal_load(pp + 1) << 1;
        id2[3*k+2] = __builtin_nontemporal_load(pp + 2) << 1;
    }

    float acc[PPT];
    #pragma unroll
    for (int k = 0; k < PPT; ++k) acc[k] = 0.0f;

    __syncthreads();                             // chunk-0 fill complete

    for (int h = 0; h < nh; ++h) {
        #pragma unroll
        for (int l = 0; l < 3; ++l) {
            int c = h * 3 + l;

            // Issue next chunk's async fill into the OTHER buffer. It has
            // the whole gather phase below to complete before the barrier.
            if (c + 1 < NC) {
                int       hn    = (l == 2) ? (h + 1) : h;     // runtime ok
                const int ln    = (l == 2) ? 0 : (l + 1);     // compile-time
                int       nbase = ((c + 1) & 1) * CN2;
                const unsigned char* src = tab + (size_t)ln * plane_b
                                               + (size_t)hn * CN2;
                int rem_b = plane_b - hn * CN2;
                int units = rem_b >= CN2 ? UNITS : ((rem_b + 1023) >> 10);
                for (int j = wid; j < units; j += TPB / 64)
                    gload_lds16(src + (size_t)j * 1024 + lane * 16,
                                ldsb + nbase + j * 1024);
            }

            // Gather chunk c from buf[c&1]:
            // sub, cmp, add, cndmask, ds_read_u16, cvt, add per attempt.
            int cb2 = h * CN2;
            int bb  = (c & 1) * CN2;
            #pragma unroll
            for (int k = 0; k < PPT; ++k) {
                u32 loc2 = (u32)(id2[3*k + l] - cb2);  // miss/-1 => huge => dummy
                int off  = loc2 < (u32)CN2 ? (bb + (int)loc2) : DUMMY2;
                union { u16 u; _Float16 hh; } cv;
                cv.u = *(const u16*)(ldsb + off);
                acc[k] += (float)cv.hh;
            }

            // Drain: next fill is done AND all waves finished reading
            // buf[c&1] before pass c+1 overwrites... (fill c+2 targets it).
            if (c + 1 < NC) __syncthreads();
        }
    }

    #pragma unroll
    for (int k = 0; k < PPT; ++k) {
        int idx = base + k * TPB;
        if (idx < n_paths) {
            int cnt = (int)(id2[3*k] >= 0) + (int)(id2[3*k+1] >= 0)
                    + (int)(id2[3*k+2] >= 0);
            float inv = (cnt == 3) ? (1.0f/3.0f) : (cnt == 2 ? 0.5f : 1.0f);
            __builtin_nontemporal_store(acc[k] * inv, out + idx);
        }
    }
}

extern "C" void kernel_launch(void* const* d_in, const int* in_sizes, int n_in,
                              void* d_out, int out_size, void* d_ws, size_t ws_size,
                              hipStream_t stream) {
    const int*   paths = (const int*)d_in[0];     // (N_PATHS, 3) int32
    const float* feat  = (const float*)d_in[1];   // (N_NODES, 128) f32
    const float* W     = (const float*)d_in[2];   // (3, 1, 128) f32
    float*       out   = (float*)d_out;           // (N_PATHS,) f32

    int n_nodes = in_sizes[1] / HIDDEN;           // 100000
    int n_paths = in_sizes[0] / 3;                // 10000000
    u16* proj_h = (u16*)d_ws;                     // 3 planes * n_nodes f16

    int nh = (n_nodes + CN - 1) / CN;             // 3 plane-chunks per plane
    size_t lds_bytes = (size_t)2 * CN2 + 4;       // 153604: double buffer

    (void)hipFuncSetAttribute((const void*)score_kernel,
            hipFuncAttributeMaxDynamicSharedMemorySize, (int)lds_bytes);
    (void)hipGetLastError();   // clear any sticky error pre-capture

    // Kernel 1: 1 wave per node, 4 waves per 256-thread block.
    {
        int blocks = (n_nodes + 3) / 4;
        proj_kernel<<<blocks, 256, 0, stream>>>(feat, W, proj_h, n_nodes);
    }

    // Kernel 2: 814 blocks, 1/CU — fill(c+1) DMA hidden under gather(c).
    {
        int blocks = (n_paths + TPB * PPT - 1) / (TPB * PPT);  // 814
        score_kernel<<<blocks, TPB, lds_bytes, stream>>>(paths, proj_h, out,
                                                         n_paths, n_nodes, nh);
    }
}